// Round 1
// baseline (127.636 us; speedup 1.0000x reference)
//
#include <hip/hip_runtime.h>
#include <math.h>

#define BB 32
#define SS 4096
#define DIN 1024
#define DOUT 1024
#define NCHUNK 32                       // s-chunks per batch row
#define ROWS_PER_BLOCK (SS / NCHUNK)    // 128
#define ROWS_PER_WAVE (ROWS_PER_BLOCK / 4) // 32
#define PART_STRIDE 1040                // floats: [0]=m, [1]=l, [16..1039]=ctx[1024]

// ---------------- kernel 1: x[b,o] = sum_i input[b,i] * W[o,i] ----------------
__global__ __launch_bounds__(256) void proj_kernel(const float* __restrict__ input,
                                                   const float* __restrict__ W,
                                                   float* __restrict__ x) {
  const int b = blockIdx.x >> 5;        // 32 o-chunks per b
  const int ochunk = blockIdx.x & 31;
  __shared__ float inp[DIN];
  const int t = threadIdx.x;
  ((float4*)inp)[t] = ((const float4*)(input + (size_t)b * DIN))[t];
  __syncthreads();
  const int wave = t >> 6, lane = t & 63;
#pragma unroll
  for (int j = 0; j < 8; ++j) {
    const int o = ochunk * 32 + wave * 8 + j;
    const float4* wrow = (const float4*)(W + (size_t)o * DIN);
    float sum = 0.f;
#pragma unroll
    for (int k = 0; k < 4; ++k) {
      float4 wv = wrow[lane + 64 * k];
      float4 iv = ((const float4*)inp)[lane + 64 * k];
      sum += wv.x * iv.x + wv.y * iv.y + wv.z * iv.z + wv.w * iv.w;
    }
#pragma unroll
    for (int off = 32; off; off >>= 1) sum += __shfl_down(sum, off);
    if (lane == 0) x[(size_t)b * DOUT + o] = sum;
  }
}

// ---- kernel 2: single pass over source_hids: scores + online softmax + ctx ----
__global__ __launch_bounds__(256) void pass_kernel(const float* __restrict__ hids,
                                                   const float* __restrict__ seg,
                                                   const float* __restrict__ x,
                                                   float* __restrict__ raw_scores,   // d_out attn region
                                                   float* __restrict__ partials) {
  const int b = blockIdx.x >> 5;        // 32 chunks per b
  const int chunk = blockIdx.x & 31;
  const int t = threadIdx.x;
  __shared__ float xs[DOUT];
  __shared__ float buf[4][DOUT];
  __shared__ float wstat[8];            // m[0..3], l[4..7]
  ((float4*)xs)[t] = ((const float4*)(x + (size_t)b * DOUT))[t];
  __syncthreads();
  const int wave = t >> 6, lane = t & 63;
  float4 xv[4];
#pragma unroll
  for (int k = 0; k < 4; ++k) xv[k] = ((const float4*)xs)[lane + 64 * k];

  const int s0 = chunk * ROWS_PER_BLOCK + wave * ROWS_PER_WAVE;
  const float* base = hids + ((size_t)b * SS + s0) * (size_t)DOUT;

  float m = -INFINITY, l = 0.f;
  float acc[16];
#pragma unroll
  for (int i = 0; i < 16; ++i) acc[i] = 0.f;

  for (int r = 0; r < ROWS_PER_WAVE; ++r) {
    const float4* row = (const float4*)(base + (size_t)r * DOUT);
    float4 h[4];
#pragma unroll
    for (int k = 0; k < 4; ++k) h[k] = row[lane + 64 * k];
    float dot = 0.f;
#pragma unroll
    for (int k = 0; k < 4; ++k)
      dot += h[k].x * xv[k].x + h[k].y * xv[k].y + h[k].z * xv[k].z + h[k].w * xv[k].w;
#pragma unroll
    for (int off = 32; off; off >>= 1) dot += __shfl_xor(dot, off);

    const int s = s0 + r;
    const float score = dot - 100.f * (1.f - seg[(size_t)b * SS + s]);
    if (lane == 0) raw_scores[(size_t)b * SS + s] = score;

    const float mnew = fmaxf(m, score);
    const float corr = __expf(m - mnew);   // first iter: exp(-inf) = 0
    const float p = __expf(score - mnew);
    l = l * corr + p;
#pragma unroll
    for (int k = 0; k < 4; ++k) {
      acc[4 * k + 0] = acc[4 * k + 0] * corr + p * h[k].x;
      acc[4 * k + 1] = acc[4 * k + 1] * corr + p * h[k].y;
      acc[4 * k + 2] = acc[4 * k + 2] * corr + p * h[k].z;
      acc[4 * k + 3] = acc[4 * k + 3] * corr + p * h[k].w;
    }
    m = mnew;
  }

  // ---- block-level combine of the 4 waves ----
  if (lane == 0) { wstat[wave] = m; wstat[4 + wave] = l; }
  __syncthreads();
  const float mb = fmaxf(fmaxf(wstat[0], wstat[1]), fmaxf(wstat[2], wstat[3]));
  const float scale = __expf(m - mb);     // per-wave scale
#pragma unroll
  for (int k = 0; k < 4; ++k) {
    ((float4*)buf[wave])[lane + 64 * k] =
        make_float4(acc[4 * k + 0] * scale, acc[4 * k + 1] * scale,
                    acc[4 * k + 2] * scale, acc[4 * k + 3] * scale);
  }
  __syncthreads();

  float* part = partials + ((size_t)b * NCHUNK + chunk) * PART_STRIDE;
  float4 v0 = ((const float4*)buf[0])[t];
  float4 v1 = ((const float4*)buf[1])[t];
  float4 v2 = ((const float4*)buf[2])[t];
  float4 v3 = ((const float4*)buf[3])[t];
  float4 c;
  c.x = v0.x + v1.x + v2.x + v3.x;
  c.y = v0.y + v1.y + v2.y + v3.y;
  c.z = v0.z + v1.z + v2.z + v3.z;
  c.w = v0.w + v1.w + v2.w + v3.w;
  ((float4*)(part + 16))[t] = c;
  if (t == 0) {
    const float lb = wstat[4] * __expf(wstat[0] - mb) + wstat[5] * __expf(wstat[1] - mb) +
                     wstat[6] * __expf(wstat[2] - mb) + wstat[7] * __expf(wstat[3] - mb);
    part[0] = mb;
    part[1] = lb;
  }
}

// ---- kernel 3: per-b merge of 32 partials -> ctx out; normalize attn in-place ----
__global__ __launch_bounds__(256) void combine_kernel(const float* __restrict__ partials,
                                                      float* __restrict__ out_ctx,
                                                      float* __restrict__ out_attn) {
  const int b = blockIdx.x;
  const int t = threadIdx.x;
  const float* pb = partials + (size_t)b * NCHUNK * PART_STRIDE;

  float m = -INFINITY;
#pragma unroll
  for (int j = 0; j < NCHUNK; ++j) m = fmaxf(m, pb[(size_t)j * PART_STRIDE]);
  float l = 0.f;
#pragma unroll
  for (int j = 0; j < NCHUNK; ++j)
    l += pb[(size_t)j * PART_STRIDE + 1] * __expf(pb[(size_t)j * PART_STRIDE] - m);
  const float inv_l = 1.f / l;

  float4 c = make_float4(0.f, 0.f, 0.f, 0.f);
  for (int j = 0; j < NCHUNK; ++j) {
    const float sc = __expf(pb[(size_t)j * PART_STRIDE] - m);
    float4 v = ((const float4*)(pb + (size_t)j * PART_STRIDE + 16))[t];
    c.x += v.x * sc; c.y += v.y * sc; c.z += v.z * sc; c.w += v.w * sc;
  }
  c.x *= inv_l; c.y *= inv_l; c.z *= inv_l; c.w *= inv_l;
  ((float4*)(out_ctx + (size_t)b * DOUT))[t] = c;

  float* arow = out_attn + (size_t)b * SS;
#pragma unroll
  for (int k = 0; k < 4; ++k) {
    float4 v = ((float4*)arow)[t + 256 * k];
    v.x = __expf(v.x - m) * inv_l;
    v.y = __expf(v.y - m) * inv_l;
    v.z = __expf(v.z - m) * inv_l;
    v.w = __expf(v.w - m) * inv_l;
    ((float4*)arow)[t + 256 * k] = v;
  }
}

extern "C" void kernel_launch(void* const* d_in, const int* in_sizes, int n_in,
                              void* d_out, int out_size, void* d_ws, size_t ws_size,
                              hipStream_t stream) {
  const float* input = (const float*)d_in[0];   // [B, DIN]
  const float* hids  = (const float*)d_in[1];   // [B, S, DOUT]
  const float* seg   = (const float*)d_in[2];   // [B, S]
  const float* W     = (const float*)d_in[3];   // [DOUT, DIN]
  float* out = (float*)d_out;
  float* out_ctx  = out;                        // [B, DOUT]
  float* out_attn = out + (size_t)BB * DOUT;    // [B, S]

  float* x        = (float*)d_ws;               // [B, DOUT]
  float* partials = x + (size_t)BB * DOUT;      // [B, NCHUNK, PART_STRIDE]

  proj_kernel<<<BB * 32, 256, 0, stream>>>(input, W, x);
  pass_kernel<<<BB * NCHUNK, 256, 0, stream>>>(hids, seg, x, out_attn, partials);
  combine_kernel<<<BB, 256, 0, stream>>>(partials, out_ctx, out_attn);
}

// Round 2
// 119.540 us; speedup vs baseline: 1.0677x; 1.0677x over previous
//
#include <hip/hip_runtime.h>
#include <math.h>

#define BB 32
#define SS 4096
#define DIN 1024
#define DOUT 1024
#define NCHUNK 32                          // s-chunks per batch row
#define ROWS_PER_BLOCK (SS / NCHUNK)       // 128
#define ROWS_PER_WAVE (ROWS_PER_BLOCK / 4) // 32
#define PART_STRIDE 1040                   // floats: [0]=m, [1]=l, [16..1039]=ctx[1024]

typedef float vf4 __attribute__((ext_vector_type(4)));

__device__ inline vf4 ntload4(const float* p) {
  return __builtin_nontemporal_load((const vf4*)p);
}

// ---------------- kernel 1: x[b,o] = sum_i input[b,i] * W[o,i] ----------------
__global__ __launch_bounds__(256) void proj_kernel(const float* __restrict__ input,
                                                   const float* __restrict__ W,
                                                   float* __restrict__ x) {
  const int b = blockIdx.x >> 5;        // 32 o-chunks per b
  const int ochunk = blockIdx.x & 31;
  __shared__ float inp[DIN];
  const int t = threadIdx.x;
  ((float4*)inp)[t] = ((const float4*)(input + (size_t)b * DIN))[t];
  __syncthreads();
  const int wave = t >> 6, lane = t & 63;
#pragma unroll
  for (int j = 0; j < 8; ++j) {
    const int o = ochunk * 32 + wave * 8 + j;
    const float4* wrow = (const float4*)(W + (size_t)o * DIN);
    float sum = 0.f;
#pragma unroll
    for (int k = 0; k < 4; ++k) {
      float4 wv = wrow[lane + 64 * k];
      float4 iv = ((const float4*)inp)[lane + 64 * k];
      sum += wv.x * iv.x + wv.y * iv.y + wv.z * iv.z + wv.w * iv.w;
    }
#pragma unroll
    for (int off = 32; off; off >>= 1) sum += __shfl_down(sum, off);
    if (lane == 0) x[(size_t)b * DOUT + o] = sum;
  }
}

// ---- kernel 2: single pass over source_hids: scores + online softmax + ctx ----
__global__ __launch_bounds__(256) void pass_kernel(const float* __restrict__ hids,
                                                   const float* __restrict__ seg,
                                                   const float* __restrict__ x,
                                                   float* __restrict__ raw_scores,   // d_out attn region
                                                   float* __restrict__ partials) {
  const int b = blockIdx.x >> 5;        // 32 chunks per b
  const int chunk = blockIdx.x & 31;
  const int t = threadIdx.x;
  __shared__ float xs[DOUT];
  __shared__ float buf[4][DOUT];
  __shared__ float sbuf[ROWS_PER_BLOCK];
  __shared__ float wstat[8];            // m[0..3], l[4..7]
  ((float4*)xs)[t] = ((const float4*)(x + (size_t)b * DOUT))[t];
  __syncthreads();
  const int wave = t >> 6, lane = t & 63;
  vf4 xv[4];
#pragma unroll
  for (int k = 0; k < 4; ++k) xv[k] = ((const vf4*)xs)[lane + 64 * k];

  const int s0 = chunk * ROWS_PER_BLOCK + wave * ROWS_PER_WAVE;
  const float* base = hids + ((size_t)b * SS + s0) * (size_t)DOUT;
  const float* segb = seg + (size_t)b * SS + s0;

  float m = -INFINITY, l = 0.f;
  vf4 acc[4];
#pragma unroll
  for (int k = 0; k < 4; ++k) acc[k] = (vf4)0.f;

  // depth-1 register prefetch pipeline over the 32 rows this wave owns
  vf4 h[4];
#pragma unroll
  for (int k = 0; k < 4; ++k) h[k] = ntload4(base + (lane + 64 * k) * 4);

#pragma unroll 4
  for (int r = 0; r < ROWS_PER_WAVE; ++r) {
    vf4 hn[4];
    if (r + 1 < ROWS_PER_WAVE) {
      const float* nb = base + (size_t)(r + 1) * DOUT;
#pragma unroll
      for (int k = 0; k < 4; ++k) hn[k] = ntload4(nb + (lane + 64 * k) * 4);
    }

    vf4 prod = h[0] * xv[0] + h[1] * xv[1] + h[2] * xv[2] + h[3] * xv[3];
    float dot = prod.x + prod.y + prod.z + prod.w;
#pragma unroll
    for (int off = 32; off; off >>= 1) dot += __shfl_xor(dot, off);

    const float score = dot - 100.f * (1.f - segb[r]);
    if (lane == 0) sbuf[wave * ROWS_PER_WAVE + r] = score;

    const float mnew = fmaxf(m, score);
    const float corr = __expf(m - mnew);   // first iter: exp(-inf) = 0
    const float p = __expf(score - mnew);
    l = l * corr + p;
#pragma unroll
    for (int k = 0; k < 4; ++k) acc[k] = acc[k] * corr + p * h[k];
    m = mnew;
#pragma unroll
    for (int k = 0; k < 4; ++k) h[k] = hn[k];
  }

  // ---- block-level combine of the 4 waves ----
  if (lane == 0) { wstat[wave] = m; wstat[4 + wave] = l; }
  __syncthreads();
  const float mb = fmaxf(fmaxf(wstat[0], wstat[1]), fmaxf(wstat[2], wstat[3]));
  const float scale = __expf(m - mb);     // per-wave scale
#pragma unroll
  for (int k = 0; k < 4; ++k)
    ((vf4*)buf[wave])[lane + 64 * k] = acc[k] * scale;
  __syncthreads();

  // coalesced raw-score write (one block: 128 contiguous floats)
  if (t < ROWS_PER_BLOCK)
    raw_scores[(size_t)b * SS + chunk * ROWS_PER_BLOCK + t] = sbuf[t];

  float* part = partials + ((size_t)b * NCHUNK + chunk) * PART_STRIDE;
  vf4 v0 = ((const vf4*)buf[0])[t];
  vf4 v1 = ((const vf4*)buf[1])[t];
  vf4 v2 = ((const vf4*)buf[2])[t];
  vf4 v3 = ((const vf4*)buf[3])[t];
  ((vf4*)(part + 16))[t] = (v0 + v1) + (v2 + v3);
  if (t == 0) {
    const float lb = wstat[4] * __expf(wstat[0] - mb) + wstat[5] * __expf(wstat[1] - mb) +
                     wstat[6] * __expf(wstat[2] - mb) + wstat[7] * __expf(wstat[3] - mb);
    part[0] = mb;
    part[1] = lb;
  }
}

// ---- kernel 3: merge partials -> ctx out; normalize attn. 4 blocks per b ----
__global__ __launch_bounds__(256) void combine_kernel(const float* __restrict__ partials,
                                                      float* __restrict__ out_ctx,
                                                      float* __restrict__ out_attn) {
  const int b = blockIdx.x >> 2;
  const int part = blockIdx.x & 3;
  const int t = threadIdx.x;
  const float* pb = partials + (size_t)b * NCHUNK * PART_STRIDE;

  __shared__ float sm[NCHUNK], sl[NCHUNK];
  if (t < NCHUNK) {
    sm[t] = pb[(size_t)t * PART_STRIDE];
    sl[t] = pb[(size_t)t * PART_STRIDE + 1];
  }
  __syncthreads();

  float m = -INFINITY;
#pragma unroll
  for (int j = 0; j < NCHUNK; ++j) m = fmaxf(m, sm[j]);
  float l = 0.f;
#pragma unroll
  for (int j = 0; j < NCHUNK; ++j) l += sl[j] * __expf(sm[j] - m);
  const float inv_l = 1.f / l;

  // this block's 256 ctx elements
  float c = 0.f;
#pragma unroll 8
  for (int j = 0; j < NCHUNK; ++j)
    c += __expf(sm[j] - m) * pb[(size_t)j * PART_STRIDE + 16 + part * 256 + t];
  out_ctx[(size_t)b * DOUT + part * 256 + t] = c * inv_l;

  // this block's 1024 attn scores (as 256 float4)
  float* arow = out_attn + (size_t)b * SS + part * 1024;
  float4 v = ((float4*)arow)[t];
  v.x = __expf(v.x - m) * inv_l;
  v.y = __expf(v.y - m) * inv_l;
  v.z = __expf(v.z - m) * inv_l;
  v.w = __expf(v.w - m) * inv_l;
  ((float4*)arow)[t] = v;
}

extern "C" void kernel_launch(void* const* d_in, const int* in_sizes, int n_in,
                              void* d_out, int out_size, void* d_ws, size_t ws_size,
                              hipStream_t stream) {
  const float* input = (const float*)d_in[0];   // [B, DIN]
  const float* hids  = (const float*)d_in[1];   // [B, S, DOUT]
  const float* seg   = (const float*)d_in[2];   // [B, S]
  const float* W     = (const float*)d_in[3];   // [DOUT, DIN]
  float* out = (float*)d_out;
  float* out_ctx  = out;                        // [B, DOUT]
  float* out_attn = out + (size_t)BB * DOUT;    // [B, S]

  float* x        = (float*)d_ws;               // [B, DOUT]
  float* partials = x + (size_t)BB * DOUT;      // [B, NCHUNK, PART_STRIDE]

  proj_kernel<<<BB * 32, 256, 0, stream>>>(input, W, x);
  pass_kernel<<<BB * NCHUNK, 256, 0, stream>>>(hids, seg, x, out_attn, partials);
  combine_kernel<<<BB * 4, 256, 0, stream>>>(partials, out_ctx, out_attn);
}